// Round 1
// baseline (2351.296 us; speedup 1.0000x reference)
//
#include <hip/hip_runtime.h>

#define B_   2
#define Q_   1568
#define C_   768
#define C2_  1536
#define H_   12
#define D_   64
#define F_   8
#define S_   196
#define N_   1568
constexpr float SCALE = 0.125f;   // d^-0.5 = 64^-0.5

// ---------------------------------------------------------------------------
// Generic tiled fp32 GEMM: C[M,N] = A[M,K] @ W[K,N] (+bias). 128x128 tile,
// 256 threads, 8x8 micro-tile. Grid = (N/128, ceil(M/128)).
// ---------------------------------------------------------------------------
__global__ __launch_bounds__(256) void gemm128(
    const float* __restrict__ A, int lda,
    const float* __restrict__ W, int ldw,
    float* __restrict__ Cm, int ldc,
    int M, int K, const float* __restrict__ bias)
{
    __shared__ float As[16 * 132];
    __shared__ float Ws[16 * 132];
    const int n0 = blockIdx.x * 128;
    const int m0 = blockIdx.y * 128;
    const int t  = threadIdx.x;
    const int tx = t & 15, ty = t >> 4;

    float acc[8][8];
#pragma unroll
    for (int i = 0; i < 8; i++)
#pragma unroll
        for (int j = 0; j < 8; j++) acc[i][j] = 0.f;

    for (int k0 = 0; k0 < K; k0 += 16) {
#pragma unroll
        for (int i = 0; i < 8; i++) {
            int e = t + 256 * i;
            int kk = e & 15, r = e >> 4;
            int m = m0 + r;
            As[kk * 132 + r] = (m < M) ? A[(size_t)m * lda + k0 + kk] : 0.f;
        }
#pragma unroll
        for (int i = 0; i < 8; i++) {
            int e = t + 256 * i;
            int n = e & 127, kk = e >> 7;
            Ws[kk * 132 + n] = W[(size_t)(k0 + kk) * ldw + n0 + n];
        }
        __syncthreads();
#pragma unroll
        for (int kk = 0; kk < 16; kk++) {
            float4 a0 = *(const float4*)&As[kk * 132 + ty * 8];
            float4 a1 = *(const float4*)&As[kk * 132 + ty * 8 + 4];
            float4 w0 = *(const float4*)&Ws[kk * 132 + tx * 8];
            float4 w1 = *(const float4*)&Ws[kk * 132 + tx * 8 + 4];
            float av[8] = {a0.x, a0.y, a0.z, a0.w, a1.x, a1.y, a1.z, a1.w};
            float wv[8] = {w0.x, w0.y, w0.z, w0.w, w1.x, w1.y, w1.z, w1.w};
#pragma unroll
            for (int i = 0; i < 8; i++)
#pragma unroll
                for (int j = 0; j < 8; j++) acc[i][j] += av[i] * wv[j];
        }
        __syncthreads();
    }

#pragma unroll
    for (int i = 0; i < 8; i++) {
        int m = m0 + ty * 8 + i;
        if (m < M) {
            float o[8];
#pragma unroll
            for (int j = 0; j < 8; j++) {
                o[j] = acc[i][j];
                if (bias) o[j] += bias[n0 + tx * 8 + j];
            }
            float* dst = Cm + (size_t)m * ldc + n0 + tx * 8;
            *(float4*)dst       = make_float4(o[0], o[1], o[2], o[3]);
            *(float4*)(dst + 4) = make_float4(o[4], o[5], o[6], o[7]);
        }
    }
}

// ---------------------------------------------------------------------------
// Stage-1 logits (output 1): out1[(b*H+h)*Q + q][n] = scale * qh . kh
// Batched [Q,64]@[64,N]^T per (b,h). 64x64 tiles, grid (25,25,24).
// ---------------------------------------------------------------------------
__global__ __launch_bounds__(256) void attn1_logits(
    const float* __restrict__ qm, const float* __restrict__ kv,
    float* __restrict__ out1)
{
    __shared__ float Qs[64 * 68];
    __shared__ float Ks[64 * 68];
    const int z = blockIdx.z;            // b*H + h
    const int b = z / H_, h = z % H_;
    const int q0 = blockIdx.y * 64, n0 = blockIdx.x * 64;
    const int t = threadIdx.x;

#pragma unroll
    for (int i = 0; i < 16; i++) {
        int e = t + 256 * i;             // 0..4095
        int dd = e & 63, r = e >> 6;
        int qq = q0 + r;
        Qs[dd * 68 + r] = (qq < Q_) ? qm[((size_t)b * Q_ + qq) * C_ + h * D_ + dd] : 0.f;
        int nn = n0 + r;
        Ks[dd * 68 + r] = (nn < N_) ? kv[((size_t)b * N_ + nn) * C2_ + h * D_ + dd] : 0.f;
    }
    __syncthreads();

    const int tx = t & 15, ty = t >> 4;
    float acc[4][4];
#pragma unroll
    for (int i = 0; i < 4; i++)
#pragma unroll
        for (int j = 0; j < 4; j++) acc[i][j] = 0.f;

#pragma unroll 4
    for (int dd = 0; dd < 64; dd++) {
        float4 a = *(const float4*)&Qs[dd * 68 + ty * 4];
        float4 w = *(const float4*)&Ks[dd * 68 + tx * 4];
        float av[4] = {a.x, a.y, a.z, a.w};
        float wv[4] = {w.x, w.y, w.z, w.w};
#pragma unroll
        for (int i = 0; i < 4; i++)
#pragma unroll
            for (int j = 0; j < 4; j++) acc[i][j] += av[i] * wv[j];
    }

#pragma unroll
    for (int i = 0; i < 4; i++) {
        int qq = q0 + ty * 4 + i;
        if (qq < Q_) {
#pragma unroll
            for (int j = 0; j < 4; j++) {
                int nn = n0 + tx * 4 + j;
                if (nn < N_)
                    out1[((size_t)z * Q_ + qq) * N_ + nn] = SCALE * acc[i][j];
            }
        }
    }
}

// ---------------------------------------------------------------------------
// Stage-1 softmax over S + PV accumulate -> x[b,q,f,h*64+dd].
// Grid (qc=8, f=8, bh=24). 196 active threads: 4 queries x 16 dims each.
// V tile (196x64) staged in LDS; logits re-read from out1 (L2-hot).
// ---------------------------------------------------------------------------
__global__ __launch_bounds__(256) void attn1_softmax_pv(
    const float* __restrict__ out1, const float* __restrict__ kv,
    float* __restrict__ x)
{
    __shared__ float Vs[S_ * 64];
    const int qc = blockIdx.x, f = blockIdx.y, z = blockIdx.z;
    const int b = z / H_, h = z % H_;
    const int t = threadIdx.x;

    // stage V tile: rows s=0..195, cols dd=0..63 (float4)
    for (int i = 0; i < 13; i++) {
        int e4 = t + 256 * i;
        if (e4 < S_ * 16) {
            int s = e4 >> 4, dd4 = e4 & 15;
            const float4* src = (const float4*)(kv + ((size_t)(b * N_ + f * S_ + s)) * C2_ + C_ + h * D_);
            ((float4*)Vs)[e4] = src[dd4];
        }
    }
    __syncthreads();

    if (t < S_) {
        const int qg = t >> 2, dg = t & 3;           // qg 0..48, dg 0..3
        const float* Lr[4];
        float m[4], su[4];
#pragma unroll
        for (int qi = 0; qi < 4; qi++) {
            int q = qc * S_ + qg * 4 + qi;
            Lr[qi] = out1 + ((size_t)z * Q_ + q) * N_ + f * S_;
            float mm = -3e38f;
            for (int s = 0; s < S_; s++) mm = fmaxf(mm, Lr[qi][s]);
            float ss = 0.f;
            for (int s = 0; s < S_; s++) ss += __expf(Lr[qi][s] - mm);
            m[qi] = mm; su[qi] = ss;
        }

        float4 acc[4][4];
#pragma unroll
        for (int qi = 0; qi < 4; qi++)
#pragma unroll
            for (int k = 0; k < 4; k++) acc[qi][k] = make_float4(0.f, 0.f, 0.f, 0.f);

        const float4* Vs4 = (const float4*)Vs;
        for (int s = 0; s < S_; s++) {
            float4 v0 = Vs4[s * 16 + dg * 4 + 0];
            float4 v1 = Vs4[s * 16 + dg * 4 + 1];
            float4 v2 = Vs4[s * 16 + dg * 4 + 2];
            float4 v3 = Vs4[s * 16 + dg * 4 + 3];
#pragma unroll
            for (int qi = 0; qi < 4; qi++) {
                float p = __expf(Lr[qi][s] - m[qi]);
                acc[qi][0].x += p * v0.x; acc[qi][0].y += p * v0.y;
                acc[qi][0].z += p * v0.z; acc[qi][0].w += p * v0.w;
                acc[qi][1].x += p * v1.x; acc[qi][1].y += p * v1.y;
                acc[qi][1].z += p * v1.z; acc[qi][1].w += p * v1.w;
                acc[qi][2].x += p * v2.x; acc[qi][2].y += p * v2.y;
                acc[qi][2].z += p * v2.z; acc[qi][2].w += p * v2.w;
                acc[qi][3].x += p * v3.x; acc[qi][3].y += p * v3.y;
                acc[qi][3].z += p * v3.z; acc[qi][3].w += p * v3.w;
            }
        }

#pragma unroll
        for (int qi = 0; qi < 4; qi++) {
            float inv = 1.f / su[qi];
            int q = qc * S_ + qg * 4 + qi;
            float* xr = x + (((size_t)(b * Q_ + q)) * F_ + f) * C_ + h * D_ + dg * 16;
#pragma unroll
            for (int k = 0; k < 4; k++) {
                float4 o = acc[qi][k];
                o.x *= inv; o.y *= inv; o.z *= inv; o.w *= inv;
                ((float4*)xr)[k] = o;
            }
        }
    }
}

// ---------------------------------------------------------------------------
// xsum[b,f,c] = sum_q x[b,q,f,c]. Grid (3, 8 qparts, 16 bf). atomicAdd.
// ---------------------------------------------------------------------------
__global__ __launch_bounds__(256) void xsum_kernel(
    const float* __restrict__ x, float* __restrict__ xsum)
{
    const int c = blockIdx.x * 256 + threadIdx.x;
    const int qp = blockIdx.y, bf = blockIdx.z;
    const int b = bf >> 3, f = bf & 7;
    float s = 0.f;
    for (int j = 0; j < S_; j++) {
        int q = qp * S_ + j;
        s += x[((size_t)(b * Q_ + q) * F_ + f) * C_ + c];
    }
    atomicAdd(&xsum[(size_t)bf * C_ + c], s);
}

// ---------------------------------------------------------------------------
// vsum[b,f,c2] = sum_c xsum[b,f,c] * Wpkv[c, 768+c2]. Grid 16 blocks.
// ---------------------------------------------------------------------------
__global__ __launch_bounds__(256) void vsum_kernel(
    const float* __restrict__ xsum, const float* __restrict__ Wpkv,
    float* __restrict__ vsum)
{
    __shared__ float xs[C_];
    const int bf = blockIdx.x;
    const int t = threadIdx.x;
    for (int i = 0; i < 3; i++) xs[t + 256 * i] = xsum[(size_t)bf * C_ + t + 256 * i];
    __syncthreads();
    for (int i = 0; i < 3; i++) {
        int c2 = t + 256 * i;
        float acc = 0.f;
        for (int c = 0; c < C_; c++) acc += xs[c] * Wpkv[(size_t)c * C2_ + C_ + c2];
        vsum[(size_t)bf * C_ + c2] = acc;
    }
}

// ---------------------------------------------------------------------------
// Stage-2: per (b,q): l2[h,f] = (scale*q2) . k2 segment; softmax over f;
// qout[b,q,c] = sum_f p2[h(c),f] * vsum[b,f,c]. Grid 3136 blocks.
// ---------------------------------------------------------------------------
__global__ __launch_bounds__(256) void attn2_qout(
    const float* __restrict__ q2, const float* __restrict__ k2,
    const float* __restrict__ vsum, float* __restrict__ qout)
{
    __shared__ float q2s[C_];
    __shared__ float l2s[96];
    __shared__ float p2s[96];
    const int bq = blockIdx.x;
    const int t = threadIdx.x;
    for (int i = 0; i < 3; i++)
        q2s[t + 256 * i] = SCALE * q2[(size_t)bq * C_ + t + 256 * i];
    __syncthreads();

    if (t < 96) {
        int h = t >> 3, fr = t & 7;
        const float4* kr4 = (const float4*)(k2 + ((size_t)bq * F_ + fr) * C_ + h * D_);
        const float4* q4  = (const float4*)&q2s[h * D_];
        float acc = 0.f;
#pragma unroll
        for (int i = 0; i < 16; i++) {
            float4 kk = kr4[i], qq = q4[i];
            acc += kk.x * qq.x + kk.y * qq.y + kk.z * qq.z + kk.w * qq.w;
        }
        l2s[t] = acc;
    }
    __syncthreads();

    if (t < H_) {
        float mm = -3e38f;
#pragma unroll
        for (int fr = 0; fr < F_; fr++) mm = fmaxf(mm, l2s[t * 8 + fr]);
        float e[F_]; float ss = 0.f;
#pragma unroll
        for (int fr = 0; fr < F_; fr++) { e[fr] = __expf(l2s[t * 8 + fr] - mm); ss += e[fr]; }
        float inv = 1.f / ss;
#pragma unroll
        for (int fr = 0; fr < F_; fr++) p2s[t * 8 + fr] = e[fr] * inv;
    }
    __syncthreads();

    const int b = bq / Q_;
    for (int i = 0; i < 3; i++) {
        int c = t + 256 * i;
        int h = c >> 6;
        float acc = 0.f;
#pragma unroll
        for (int fr = 0; fr < F_; fr++)
            acc += p2s[h * 8 + fr] * vsum[((size_t)(b * F_ + fr)) * C_ + c];
        qout[(size_t)bq * C_ + c] = acc;
    }
}

// ---------------------------------------------------------------------------
extern "C" void kernel_launch(void* const* d_in, const int* in_sizes, int n_in,
                              void* d_out, int out_size, void* d_ws, size_t ws_size,
                              hipStream_t stream) {
    const float* query  = (const float*)d_in[0];
    const float* memory = (const float*)d_in[1];
    const float* Wq     = (const float*)d_in[2];
    const float* Wkv    = (const float*)d_in[3];
    const float* Wpq    = (const float*)d_in[4];
    const float* Wpkv   = (const float*)d_in[5];
    const float* Wproj  = (const float*)d_in[6];
    const float* bproj  = (const float*)d_in[7];

    float* out0 = (float*)d_out;                              // [B,Q,C]
    float* out1 = (float*)d_out + (size_t)B_ * Q_ * C_;       // [B*H,Q,F,S]

    float* ws   = (float*)d_ws;
    float* q    = ws;                  // 2,408,448
    float* kv   = ws + 2408448;        // 4,816,896
    float* q2   = ws + 7225344;        // 2,408,448
    float* x    = ws + 9633792;        // 19,267,584
    float* k2   = ws + 28901376;       // 19,267,584
    float* xsum = ws + 48168960;       // 12,288
    float* vsum = ws + 48181248;       // 12,288
    float* qout = q;                   // reuse q buffer (dead after logits)

    // q = query @ Wq
    gemm128<<<dim3(6, 25), 256, 0, stream>>>(query, C_, Wq, C_, q, C_, B_ * Q_, C_, nullptr);
    // kv = memory @ Wkv
    gemm128<<<dim3(12, 25), 256, 0, stream>>>(memory, C_, Wkv, C2_, kv, C2_, B_ * N_, C_, nullptr);
    // q2 = q @ Wpq
    gemm128<<<dim3(6, 25), 256, 0, stream>>>(q, C_, Wpq, C_, q2, C_, B_ * Q_, C_, nullptr);
    // output 1: pre-softmax scaled logits
    attn1_logits<<<dim3(25, 25, 24), 256, 0, stream>>>(q, kv, out1);
    // softmax + PV -> x
    attn1_softmax_pv<<<dim3(8, 8, 24), 256, 0, stream>>>(out1, kv, x);
    // k2 = x @ Wpkv[:, :768]
    gemm128<<<dim3(6, 196), 256, 0, stream>>>(x, C_, Wpkv, C2_, k2, C_, B_ * Q_ * F_, C_, nullptr);
    // xsum over q, then vsum = xsum @ Wpkv[:, 768:]
    hipMemsetAsync(xsum, 0, (size_t)B_ * F_ * C_ * sizeof(float), stream);
    xsum_kernel<<<dim3(3, 8, 16), 256, 0, stream>>>(x, xsum);
    vsum_kernel<<<16, 256, 0, stream>>>(xsum, Wpkv, vsum);
    // stage-2 attention -> qout (pre-projection)
    attn2_qout<<<3136, 256, 0, stream>>>(q2, k2, vsum, qout);
    // out0 = qout @ Wproj + bproj
    gemm128<<<dim3(6, 25), 256, 0, stream>>>(qout, C_, Wproj, C_, out0, C_, B_ * Q_, C_, bproj);
}

// Round 2
// 1237.169 us; speedup vs baseline: 1.9005x; 1.9005x over previous
//
#include <hip/hip_runtime.h>

#define B_   2
#define Q_   1568
#define C_   768
#define C2_  1536
#define H_   12
#define D_   64
#define F_   8
#define S_   196
#define N_   1568
constexpr float SCALE = 0.125f;   // d^-0.5 = 64^-0.5

typedef __bf16 bf16_t;
typedef __bf16 bf16x8 __attribute__((ext_vector_type(8)));
typedef __bf16 bf16x4 __attribute__((ext_vector_type(4)));
typedef float  f32x4  __attribute__((ext_vector_type(4)));

#define AS_G __attribute__((address_space(1)))
#define AS_L __attribute__((address_space(3)))

__device__ inline void load_lds16(const void* g, void* l) {
    __builtin_amdgcn_global_load_lds((const AS_G unsigned int*)g,
                                     (AS_L unsigned int*)l, 16, 0, 0);
}

// ---------------------------------------------------------------------------
// fp32 -> bf16 elementwise convert (n % 4 == 0)
// ---------------------------------------------------------------------------
__global__ __launch_bounds__(256) void cvt_bf16(
    const float* __restrict__ in, bf16_t* __restrict__ out, int n4)
{
    int i = blockIdx.x * 256 + threadIdx.x;
    if (i < n4) {
        float4 v = ((const float4*)in)[i];
        bf16x4 o = { (bf16_t)v.x, (bf16_t)v.y, (bf16_t)v.z, (bf16_t)v.w };
        ((bf16x4*)out)[i] = o;
    }
}

// ---------------------------------------------------------------------------
// W[K,N] fp32 -> Wt[N,K] bf16 (transpose+convert). K,N % 32 == 0.
// Grid (N/32, K/32), 256 threads.
// ---------------------------------------------------------------------------
__global__ __launch_bounds__(256) void transpose_cvt(
    const float* __restrict__ W, bf16_t* __restrict__ Wt, int K, int N)
{
    __shared__ float tile[32][33];
    const int k0 = blockIdx.y * 32, n0 = blockIdx.x * 32;
    const int t = threadIdx.x;
    const int tx = t & 31, ty = t >> 5;          // ty 0..7
#pragma unroll
    for (int i = 0; i < 4; i++)
        tile[ty + i * 8][tx] = W[(size_t)(k0 + ty + i * 8) * N + n0 + tx];
    __syncthreads();
#pragma unroll
    for (int i = 0; i < 4; i++)
        Wt[(size_t)(n0 + ty + i * 8) * K + k0 + tx] = (bf16_t)tile[tx][ty + i * 8];
}

// ---------------------------------------------------------------------------
// bf16 MFMA GEMM: C[M,N] = A[M,K] @ Bt[N,K]^T (+bias), C fp32, optional Cbf.
// 128x128 tile, BK=32, 256 threads (4 waves, each 64x64 via 4x4 16x16 MFMAs).
// Grid (N/128, ceil(M/128)). K % 32 == 0, N % 128 == 0.
// ---------------------------------------------------------------------------
__global__ __launch_bounds__(256) void gemm_mfma(
    const bf16_t* __restrict__ A, const bf16_t* __restrict__ Bt,
    float* __restrict__ C, bf16_t* __restrict__ Cbf,
    int M, int N, int K, const float* __restrict__ bias)
{
    __shared__ bf16_t As[128 * 32];
    __shared__ bf16_t Bs[128 * 32];
    const int n0 = blockIdx.x * 128;
    const int m0 = blockIdx.y * 128;
    const int t = threadIdx.x;
    const int lane = t & 63;
    const int wv = t >> 6;                 // wave 0..3
    const int wm = wv >> 1, wn = wv & 1;   // 2x2 wave grid, 64x64 each
    const int lane15 = lane & 15, quad = lane >> 4;

    f32x4 acc[4][4];
#pragma unroll
    for (int i = 0; i < 4; i++)
#pragma unroll
        for (int j = 0; j < 4; j++) acc[i][j] = (f32x4){0.f, 0.f, 0.f, 0.f};

    for (int k0 = 0; k0 < K; k0 += 32) {
        // stage A,B tiles: 512 chunks of 16B each (row-major [128][32] bf16)
#pragma unroll
        for (int half = 0; half < 2; half++) {
            int c = half * 256 + t;        // chunk id 0..511
            int row = c >> 2, kc = c & 2 ? (c & 3) : (c & 3); // c&3
            kc = c & 3;
            int rg = m0 + row; if (rg >= M) rg = M - 1;
            load_lds16(A + (size_t)rg * K + k0 + kc * 8,
                       (char*)As + (half * 256 + wv * 64) * 16);
            load_lds16(Bt + (size_t)(n0 + row) * K + k0 + kc * 8,
                       (char*)Bs + (half * 256 + wv * 64) * 16);
        }
        __syncthreads();

        bf16x8 af[4], bfr[4];
#pragma unroll
        for (int i = 0; i < 4; i++) {
            af[i]  = *(const bf16x8*)(As + (wm * 64 + i * 16 + lane15) * 32 + quad * 8);
            bfr[i] = *(const bf16x8*)(Bs + (wn * 64 + i * 16 + lane15) * 32 + quad * 8);
        }
#pragma unroll
        for (int i = 0; i < 4; i++)
#pragma unroll
            for (int j = 0; j < 4; j++)
                acc[i][j] = __builtin_amdgcn_mfma_f32_16x16x32_bf16(af[i], bfr[j], acc[i][j], 0, 0, 0);
        __syncthreads();
    }

#pragma unroll
    for (int i = 0; i < 4; i++) {
#pragma unroll
        for (int j = 0; j < 4; j++) {
            int col = n0 + wn * 64 + j * 16 + lane15;
            float bb = bias ? bias[col] : 0.f;
#pragma unroll
            for (int r = 0; r < 4; r++) {
                int row = m0 + wm * 64 + i * 16 + quad * 4 + r;
                if (row < M) {
                    float v = acc[i][j][r] + bb;
                    C[(size_t)row * N + col] = v;
                    if (Cbf) Cbf[(size_t)row * N + col] = (bf16_t)v;
                }
            }
        }
    }
}

// ---------------------------------------------------------------------------
// Stage-1 logits (output 1): out1[(b*H+h)*Q + q][n] = scale * qh . kh
// ---------------------------------------------------------------------------
__global__ __launch_bounds__(256) void attn1_logits(
    const float* __restrict__ qm, const float* __restrict__ kv,
    float* __restrict__ out1)
{
    __shared__ float Qs[64 * 68];
    __shared__ float Ks[64 * 68];
    const int z = blockIdx.z;            // b*H + h
    const int b = z / H_, h = z % H_;
    const int q0 = blockIdx.y * 64, n0 = blockIdx.x * 64;
    const int t = threadIdx.x;

#pragma unroll
    for (int i = 0; i < 16; i++) {
        int e = t + 256 * i;             // 0..4095
        int dd = e & 63, r = e >> 6;
        int qq = q0 + r;
        Qs[dd * 68 + r] = (qq < Q_) ? qm[((size_t)b * Q_ + qq) * C_ + h * D_ + dd] : 0.f;
        int nn = n0 + r;
        Ks[dd * 68 + r] = (nn < N_) ? kv[((size_t)b * N_ + nn) * C2_ + h * D_ + dd] : 0.f;
    }
    __syncthreads();

    const int tx = t & 15, ty = t >> 4;
    float acc[4][4];
#pragma unroll
    for (int i = 0; i < 4; i++)
#pragma unroll
        for (int j = 0; j < 4; j++) acc[i][j] = 0.f;

#pragma unroll 4
    for (int dd = 0; dd < 64; dd++) {
        float4 a = *(const float4*)&Qs[dd * 68 + ty * 4];
        float4 w = *(const float4*)&Ks[dd * 68 + tx * 4];
        float av[4] = {a.x, a.y, a.z, a.w};
        float wv[4] = {w.x, w.y, w.z, w.w};
#pragma unroll
        for (int i = 0; i < 4; i++)
#pragma unroll
            for (int j = 0; j < 4; j++) acc[i][j] += av[i] * wv[j];
    }

#pragma unroll
    for (int i = 0; i < 4; i++) {
        int qq = q0 + ty * 4 + i;
        if (qq < Q_) {
#pragma unroll
            for (int j = 0; j < 4; j++) {
                int nn = n0 + tx * 4 + j;
                if (nn < N_)
                    out1[((size_t)z * Q_ + qq) * N_ + nn] = SCALE * acc[i][j];
            }
        }
    }
}

// ---------------------------------------------------------------------------
// Stage-1 softmax over S + PV accumulate -> x_bf[b,q,f,h*64+dd] (bf16).
// Grid (qc=8, f=8, bh=24). 196 active threads: 4 queries x 16 dims each.
// ---------------------------------------------------------------------------
__global__ __launch_bounds__(256) void attn1_softmax_pv(
    const float* __restrict__ out1, const float* __restrict__ kv,
    bf16_t* __restrict__ x)
{
    __shared__ float Vs[S_ * 64];
    const int qc = blockIdx.x, f = blockIdx.y, z = blockIdx.z;
    const int b = z / H_, h = z % H_;
    const int t = threadIdx.x;

    for (int i = 0; i < 13; i++) {
        int e4 = t + 256 * i;
        if (e4 < S_ * 16) {
            int s = e4 >> 4, dd4 = e4 & 15;
            const float4* src = (const float4*)(kv + ((size_t)(b * N_ + f * S_ + s)) * C2_ + C_ + h * D_);
            ((float4*)Vs)[e4] = src[dd4];
        }
    }
    __syncthreads();

    if (t < S_) {
        const int qg = t >> 2, dg = t & 3;
        const float* Lr[4];
        float m[4], su[4];
#pragma unroll
        for (int qi = 0; qi < 4; qi++) {
            int q = qc * S_ + qg * 4 + qi;
            Lr[qi] = out1 + ((size_t)z * Q_ + q) * N_ + f * S_;
            float mm = -3e38f;
            for (int s = 0; s < S_; s++) mm = fmaxf(mm, Lr[qi][s]);
            float ss = 0.f;
            for (int s = 0; s < S_; s++) ss += __expf(Lr[qi][s] - mm);
            m[qi] = mm; su[qi] = ss;
        }

        float4 acc[4][4];
#pragma unroll
        for (int qi = 0; qi < 4; qi++)
#pragma unroll
            for (int k = 0; k < 4; k++) acc[qi][k] = make_float4(0.f, 0.f, 0.f, 0.f);

        const float4* Vs4 = (const float4*)Vs;
        for (int s = 0; s < S_; s++) {
            float4 v0 = Vs4[s * 16 + dg * 4 + 0];
            float4 v1 = Vs4[s * 16 + dg * 4 + 1];
            float4 v2 = Vs4[s * 16 + dg * 4 + 2];
            float4 v3 = Vs4[s * 16 + dg * 4 + 3];
#pragma unroll
            for (int qi = 0; qi < 4; qi++) {
                float p = __expf(Lr[qi][s] - m[qi]);
                acc[qi][0].x += p * v0.x; acc[qi][0].y += p * v0.y;
                acc[qi][0].z += p * v0.z; acc[qi][0].w += p * v0.w;
                acc[qi][1].x += p * v1.x; acc[qi][1].y += p * v1.y;
                acc[qi][1].z += p * v1.z; acc[qi][1].w += p * v1.w;
                acc[qi][2].x += p * v2.x; acc[qi][2].y += p * v2.y;
                acc[qi][2].z += p * v2.z; acc[qi][2].w += p * v2.w;
                acc[qi][3].x += p * v3.x; acc[qi][3].y += p * v3.y;
                acc[qi][3].z += p * v3.z; acc[qi][3].w += p * v3.w;
            }
        }

#pragma unroll
        for (int qi = 0; qi < 4; qi++) {
            float inv = 1.f / su[qi];
            int q = qc * S_ + qg * 4 + qi;
            bf16_t* xr = x + (((size_t)(b * Q_ + q)) * F_ + f) * C_ + h * D_ + dg * 16;
#pragma unroll
            for (int k = 0; k < 4; k++) {
                float4 o = acc[qi][k];
                bf16x4 ov = { (bf16_t)(o.x * inv), (bf16_t)(o.y * inv),
                              (bf16_t)(o.z * inv), (bf16_t)(o.w * inv) };
                *(bf16x4*)(xr + k * 4) = ov;
            }
        }
    }
}

// ---------------------------------------------------------------------------
// xsum[b,f,c] = sum_q x[b,q,f,c] (x in bf16). Grid (3, 8, 16). atomicAdd.
// ---------------------------------------------------------------------------
__global__ __launch_bounds__(256) void xsum_kernel(
    const bf16_t* __restrict__ x, float* __restrict__ xsum)
{
    const int c = blockIdx.x * 256 + threadIdx.x;
    const int qp = blockIdx.y, bf = blockIdx.z;
    const int b = bf >> 3, f = bf & 7;
    float s = 0.f;
    for (int j = 0; j < S_; j++) {
        int q = qp * S_ + j;
        s += (float)x[((size_t)(b * Q_ + q) * F_ + f) * C_ + c];
    }
    atomicAdd(&xsum[(size_t)bf * C_ + c], s);
}

// ---------------------------------------------------------------------------
// vsum[b,f,c2] = sum_c xsum[b,f,c] * Wpkv[c, 768+c2]. Grid 16 blocks.
// ---------------------------------------------------------------------------
__global__ __launch_bounds__(256) void vsum_kernel(
    const float* __restrict__ xsum, const float* __restrict__ Wpkv,
    float* __restrict__ vsum)
{
    __shared__ float xs[C_];
    const int bf = blockIdx.x;
    const int t = threadIdx.x;
    for (int i = 0; i < 3; i++) xs[t + 256 * i] = xsum[(size_t)bf * C_ + t + 256 * i];
    __syncthreads();
    for (int i = 0; i < 3; i++) {
        int c2 = t + 256 * i;
        float acc = 0.f;
        for (int c = 0; c < C_; c++) acc += xs[c] * Wpkv[(size_t)c * C2_ + C_ + c2];
        vsum[(size_t)bf * C_ + c2] = acc;
    }
}

// ---------------------------------------------------------------------------
// Stage-2: softmax over f, then qout[b,q,c] = sum_f p2 * vsum. Out bf16.
// ---------------------------------------------------------------------------
__global__ __launch_bounds__(256) void attn2_qout(
    const float* __restrict__ q2, const float* __restrict__ k2,
    const float* __restrict__ vsum, bf16_t* __restrict__ qout)
{
    __shared__ float q2s[C_];
    __shared__ float l2s[96];
    __shared__ float p2s[96];
    const int bq = blockIdx.x;
    const int t = threadIdx.x;
    for (int i = 0; i < 3; i++)
        q2s[t + 256 * i] = SCALE * q2[(size_t)bq * C_ + t + 256 * i];
    __syncthreads();

    if (t < 96) {
        int h = t >> 3, fr = t & 7;
        const float4* kr4 = (const float4*)(k2 + ((size_t)bq * F_ + fr) * C_ + h * D_);
        const float4* q4  = (const float4*)&q2s[h * D_];
        float acc = 0.f;
#pragma unroll
        for (int i = 0; i < 16; i++) {
            float4 kk = kr4[i], qq = q4[i];
            acc += kk.x * qq.x + kk.y * qq.y + kk.z * qq.z + kk.w * qq.w;
        }
        l2s[t] = acc;
    }
    __syncthreads();

    if (t < H_) {
        float mm = -3e38f;
#pragma unroll
        for (int fr = 0; fr < F_; fr++) mm = fmaxf(mm, l2s[t * 8 + fr]);
        float e[F_]; float ss = 0.f;
#pragma unroll
        for (int fr = 0; fr < F_; fr++) { e[fr] = __expf(l2s[t * 8 + fr] - mm); ss += e[fr]; }
        float inv = 1.f / ss;
#pragma unroll
        for (int fr = 0; fr < F_; fr++) p2s[t * 8 + fr] = e[fr] * inv;
    }
    __syncthreads();

    const int b = bq / Q_;
    for (int i = 0; i < 3; i++) {
        int c = t + 256 * i;
        int h = c >> 6;
        float acc = 0.f;
#pragma unroll
        for (int fr = 0; fr < F_; fr++)
            acc += p2s[h * 8 + fr] * vsum[((size_t)(b * F_ + fr)) * C_ + c];
        qout[(size_t)bq * C_ + c] = (bf16_t)acc;
    }
}

// ---------------------------------------------------------------------------
extern "C" void kernel_launch(void* const* d_in, const int* in_sizes, int n_in,
                              void* d_out, int out_size, void* d_ws, size_t ws_size,
                              hipStream_t stream) {
    const float* query  = (const float*)d_in[0];
    const float* memory = (const float*)d_in[1];
    const float* Wq     = (const float*)d_in[2];
    const float* Wkv    = (const float*)d_in[3];
    const float* Wpq    = (const float*)d_in[4];
    const float* Wpkv   = (const float*)d_in[5];
    const float* Wproj  = (const float*)d_in[6];
    const float* bproj  = (const float*)d_in[7];

    float* out0 = (float*)d_out;                              // [B,Q,C]
    float* out1 = (float*)d_out + (size_t)B_ * Q_ * C_;       // [B*H,Q,F,S]

    char* w = (char*)d_ws;                                    // byte offsets, all 16B aligned
    float*  qf    = (float*) (w + 0);            //  9,633,792 B  [B*Q, C]
    float*  kvf   = (float*) (w + 9633792);      // 19,267,584 B  [B*N, 2C]
    float*  q2f   = (float*) (w + 28901376);     //  9,633,792 B  [B*Q, C]
    float*  k2f   = (float*) (w + 38535168);     // 77,070,336 B  [B*Q*F, C]
    bf16_t* x_bf  = (bf16_t*)(w + 115605504);    // 38,535,168 B  [B*Q*F, C]
    bf16_t* qry_b = (bf16_t*)(w + 154140672);    //  4,816,896 B
    bf16_t* mem_b = (bf16_t*)(w + 158957568);    //  4,816,896 B
    bf16_t* q_bf  = (bf16_t*)(w + 163774464);    //  4,816,896 B
    bf16_t* qo_bf = (bf16_t*)(w + 168591360);    //  4,816,896 B
    bf16_t* Wqt   = (bf16_t*)(w + 173408256);    //  1,179,648 B  [768,768]
    bf16_t* Wkvt  = (bf16_t*)(w + 174587904);    //  2,359,296 B  [1536,768]
    bf16_t* Wpqt  = (bf16_t*)(w + 176947200);    //  1,179,648 B
    bf16_t* Wpkvt = (bf16_t*)(w + 178126848);    //  2,359,296 B  [1536,768]
    bf16_t* Wprjt = (bf16_t*)(w + 180486144);    //  1,179,648 B
    float*  xsum  = (float*) (w + 181665792);    //     49,152 B
    float*  vsum  = (float*) (w + 181714944);    //     49,152 B

    const int MQ = B_ * Q_;        // 3136
    const int MN = B_ * N_;        // 3136
    const int MX = B_ * Q_ * F_;   // 25088

    // input conversions
    cvt_bf16<<<2352, 256, 0, stream>>>(query,  qry_b, MQ * C_ / 4);
    cvt_bf16<<<2352, 256, 0, stream>>>(memory, mem_b, MN * C_ / 4);
    transpose_cvt<<<dim3(24, 24), 256, 0, stream>>>(Wq,    Wqt,   C_, C_);
    transpose_cvt<<<dim3(48, 24), 256, 0, stream>>>(Wkv,   Wkvt,  C_, C2_);
    transpose_cvt<<<dim3(24, 24), 256, 0, stream>>>(Wpq,   Wpqt,  C_, C_);
    transpose_cvt<<<dim3(48, 24), 256, 0, stream>>>(Wpkv,  Wpkvt, C_, C2_);
    transpose_cvt<<<dim3(24, 24), 256, 0, stream>>>(Wproj, Wprjt, C_, C_);

    // q = query @ Wq   (fp32 for logits, bf16 for q2 gemm)
    gemm_mfma<<<dim3(6, 25), 256, 0, stream>>>(qry_b, Wqt, qf, q_bf, MQ, C_, C_, nullptr);
    // kv = memory @ Wkv
    gemm_mfma<<<dim3(12, 25), 256, 0, stream>>>(mem_b, Wkvt, kvf, nullptr, MN, C2_, C_, nullptr);
    // q2 = q @ Wpq
    gemm_mfma<<<dim3(6, 25), 256, 0, stream>>>(q_bf, Wpqt, q2f, nullptr, MQ, C_, C_, nullptr);
    // output 1: pre-softmax scaled logits (fp32)
    attn1_logits<<<dim3(25, 25, 24), 256, 0, stream>>>(qf, kvf, out1);
    // softmax + PV -> x (bf16)
    attn1_softmax_pv<<<dim3(8, 8, 24), 256, 0, stream>>>(out1, kvf, x_bf);
    // k2 = x @ Wpkv[:, :768]  (Wpkvt rows 0..767 are Wpkv_k^T)
    gemm_mfma<<<dim3(6, 196), 256, 0, stream>>>(x_bf, Wpkvt, k2f, nullptr, MX, C_, C_, nullptr);
    // xsum over q, vsum = xsum @ Wpkv[:, 768:]
    hipMemsetAsync(xsum, 0, (size_t)B_ * F_ * C_ * sizeof(float), stream);
    xsum_kernel<<<dim3(3, 8, 16), 256, 0, stream>>>(x_bf, xsum);
    vsum_kernel<<<16, 256, 0, stream>>>(xsum, Wpkv, vsum);
    // stage-2 attention -> qout (bf16, pre-projection)
    attn2_qout<<<3136, 256, 0, stream>>>(q2f, k2f, vsum, qo_bf);
    // out0 = qout @ Wproj + bproj
    gemm_mfma<<<dim3(6, 25), 256, 0, stream>>>(qo_bf, Wprjt, out0, nullptr, MQ, C_, C_, bproj);
}